// Round 13
// baseline (69.901 us; speedup 1.0000x reference)
//
#include <hip/hip_runtime.h>

#define NELEM 21600
#define KSEL 1000
#define MAXB 18
#define NT 1024
#define CAP 2048
#define NCHUNK 4
#define QC 8100                     // float4s per K1 block (32400/4)
#define QK 5400                     // keys per K2 block (21600/4)
#define NFULL 21                    // fallback: 21*1024 = 21504
#define NTAIL (NELEM - NFULL * NT)  // 96

typedef unsigned long long ull;

// monotone map: ascending uint key <-> ascending float
__device__ __forceinline__ unsigned fkey(float f) {
  unsigned u = __float_as_uint(f);
  return (u & 0x80000000u) ? ~u : (u | 0x80000000u);
}
__device__ __forceinline__ float unfkey(unsigned k) {
  unsigned u = (k & 0x80000000u) ? (k ^ 0x80000000u) : ~k;
  return __uint_as_float(u);
}

// ---------------- K1: full-chip float4 scan -> keys + chunk hists --------------
__global__ __launch_bounds__(NT) void k1_scan(
    const float* __restrict__ x, unsigned* __restrict__ gkeys,
    unsigned* __restrict__ ghist, unsigned* __restrict__ gcnt,
    unsigned* __restrict__ gflag) {
  const int blk = blockIdx.x;
  const int s = blk >> 2, c = blk & 3;
  const int t = threadIdx.x;
  const float4* xq = (const float4*)(x + (size_t)s * NELEM * 6);
  unsigned* gk = gkeys + (size_t)s * NELEM;

  __shared__ unsigned h[2048];
  h[2 * t] = 0u; h[2 * t + 1] = 0u;
  if (c == 0 && t == 0) { gcnt[s] = 0u; gflag[s] = 0u; }
  __syncthreads();

  const int base = c * QC;
  #pragma unroll
  for (int k = 0; k < 8; ++k) {
    int off = t + (k << 10);
    if (k < 7 || off < QC) {
      int g = base + off;
      float4 v = xq[g];
      int r = g % 3;
      if (r == 0) {
        unsigned key = fkey(v.x);
        gk[2 * (g / 3)] = key;
        atomicAdd(&h[key >> 21], 1u);
      } else if (r == 1) {
        unsigned key = fkey(v.z);
        gk[2 * (g / 3) + 1] = key;
        atomicAdd(&h[key >> 21], 1u);
      }
    }
  }
  __syncthreads();
  unsigned* gh = ghist + (size_t)blk * 2048;
  gh[2 * t] = h[2 * t];
  gh[2 * t + 1] = h[2 * t + 1];
}

// Wave-shuffle bucket select over hist[2048]. 16 waves x 128 buckets.
__device__ void select_bucket(const unsigned* hist, unsigned target,
                              volatile unsigned* chunkSuf,
                              unsigned* outB, unsigned* outCnt, unsigned* outAbove) {
  const int tid = threadIdx.x;
  const int w = tid >> 6, l = tid & 63;
  unsigned h1 = hist[w * 128 + 2 * l + 1];
  unsigned s = hist[w * 128 + 2 * l] + h1;
  #pragma unroll
  for (int d = 1; d < 64; d <<= 1) {
    unsigned t = __shfl_down(s, d);
    if (l + d < 64) s += t;
  }
  if (l == 0) chunkSuf[w] = s;
  __syncthreads();
  if (w == 0) {
    unsigned ct = (l < 16) ? chunkSuf[l] : 0u;
    unsigned cs = ct;
    #pragma unroll
    for (int d = 1; d < 16; d <<= 1) {
      unsigned t = __shfl_down(cs, d);
      if (l + d < 16) cs += t;
    }
    if (l < 16) chunkSuf[l] = cs - ct;
  }
  __syncthreads();
  unsigned base = chunkSuf[w];
  unsigned sufE = s + base;
  unsigned sN = __shfl_down(s, 1);
  unsigned sufN = ((l < 63) ? sN : 0u) + base;
  unsigned geOdd = sufN + h1;
  if (sufE >= target && geOdd < target) { *outB = w * 128u + 2u * l;     *outCnt = sufE;  *outAbove = geOdd; }
  if (geOdd >= target && sufN < target) { *outB = w * 128u + 2u * l + 1; *outCnt = geOdd; *outAbove = sufN;  }
  __syncthreads();
}

// ---------------- K2: full-chip threshold + compact (4 blocks/sample) ----------
__global__ __launch_bounds__(NT) void k2_compact(
    const unsigned* __restrict__ gkeys, const unsigned* __restrict__ ghist,
    ull* __restrict__ gselPk, unsigned* __restrict__ gcnt,
    unsigned* __restrict__ gflag) {
  const int blk = blockIdx.x;
  const int s = blk >> 2, q = blk & 3;
  const int tid = threadIdx.x;

  __shared__ unsigned hist[2048];
  __shared__ unsigned chunkSuf[16];
  __shared__ ull lbuf[CAP];
  __shared__ unsigned lcnt, gbase;
  __shared__ unsigned sB, sCnt, sAbove;

  {
    unsigned h0 = 0, h1 = 0;
    #pragma unroll
    for (int c = 0; c < NCHUNK; ++c) {
      const unsigned* gh = ghist + (size_t)(s * NCHUNK + c) * 2048;
      h0 += gh[2 * tid];
      h1 += gh[2 * tid + 1];
    }
    hist[2 * tid] = h0; hist[2 * tid + 1] = h1;
  }
  if (tid == 0) lcnt = 0u;
  __syncthreads();
  select_bucket(hist, KSEL, chunkSuf, &sB, &sCnt, &sAbove);

  if (sCnt > (unsigned)CAP) {                 // astronomically rare tie storm
    if (tid == 0 && q == 0) gflag[s] = 1u;
    return;
  }
  const unsigned TB = sB << 21;
  const unsigned* ks = gkeys + (size_t)s * NELEM + q * QK;
  const int lw = tid & 63;
  #pragma unroll
  for (int it = 0; it < 6; ++it) {
    int i = tid + (it << 10);
    bool pred = false;
    unsigned k = 0u;
    if (i < QK) { k = ks[i]; pred = (k >= TB); }
    ull mask = __ballot(pred);
    if (mask) {
      int leader = __builtin_ctzll(mask);
      unsigned tot = (unsigned)__popcll(mask);
      unsigned bp = 0;
      if (lw == leader) bp = atomicAdd(&lcnt, tot);
      bp = __shfl(bp, leader);
      if (pred) {
        unsigned p = bp + (unsigned)__popcll(mask & ((1ull << lw) - 1ull));
        unsigned idx = (unsigned)(q * QK + i);
        lbuf[p] = ((ull)k << 32) | (unsigned)(~idx);
      }
    }
  }
  __syncthreads();
  if (tid == 0) gbase = atomicAdd(&gcnt[s], lcnt);
  __syncthreads();
  ull* gs = gselPk + (size_t)s * CAP;
  const unsigned n = lcnt, b0 = gbase;
  for (unsigned i = tid; i < n; i += NT) gs[b0 + i] = lbuf[i];
}

// ---------------- K3: per-sample sort + decode + NMS + output ------------------
__global__ __launch_bounds__(NT, 4) void k3_final(
    const float* __restrict__ x, const float* __restrict__ anch,
    const unsigned* __restrict__ gkeys, const unsigned* __restrict__ ghist,
    const ull* __restrict__ gselPk, const unsigned* __restrict__ gcnt,
    const unsigned* __restrict__ gflag, float* __restrict__ out) {
  const int s = blockIdx.x;
  const int tid = threadIdx.x;
  const float* xb = x + (size_t)s * NELEM * 6;

  __shared__ ull selPk[CAP];
  __shared__ float px1[1088], py1[1088], px2[1088], py2[1088];
  __shared__ unsigned hist[2048];
  __shared__ unsigned chunkSuf[16];
  __shared__ unsigned sB, sCnt, sAbove;
  __shared__ unsigned cnt;
  __shared__ int keptRank[MAXB];
  __shared__ int numKept;

  if (gflag[s] == 0u) {
    // ---- fast path: coalesced load of the pre-compacted candidates ----
    const unsigned n = gcnt[s];
    const ull* gs = gselPk + (size_t)s * CAP;
    for (unsigned i = tid; i < CAP; i += NT) selPk[i] = (i < n) ? gs[i] : 0ull;
    __syncthreads();
  } else {
    // ---- rare fallback: in-block exact select (22-bit refine) + compact ----
    const unsigned* ks = gkeys + (size_t)s * NELEM;
    unsigned kv[NFULL];
    #pragma unroll
    for (int u = 0; u < NFULL; ++u) kv[u] = ks[tid + (u << 10)];
    unsigned ktail = 0u;
    const bool hastail = tid < NTAIL;
    if (hastail) ktail = ks[tid + NFULL * NT];
    {
      unsigned h0 = 0, h1 = 0;
      #pragma unroll
      for (int c = 0; c < NCHUNK; ++c) {
        const unsigned* gh = ghist + (size_t)(s * NCHUNK + c) * 2048;
        h0 += gh[2 * tid];
        h1 += gh[2 * tid + 1];
      }
      hist[2 * tid] = h0; hist[2 * tid + 1] = h1;
    }
    __syncthreads();
    select_bucket(hist, KSEL, chunkSuf, &sB, &sCnt, &sAbove);
    const unsigned b1 = sB, above1 = sAbove;
    // refine to 22 bits (this branch means the 11-bit bucket was huge)
    hist[2 * tid] = 0u; hist[2 * tid + 1] = 0u;
    __syncthreads();
    #pragma unroll
    for (int u = 0; u < NFULL; ++u)
      if ((kv[u] >> 21) == b1) atomicAdd(&hist[(kv[u] >> 10) & 0x7FFu], 1u);
    if (hastail && (ktail >> 21) == b1) atomicAdd(&hist[(ktail >> 10) & 0x7FFu], 1u);
    __syncthreads();
    select_bucket(hist, KSEL - above1, chunkSuf, &sB, &sCnt, &sAbove);
    const unsigned TB = (b1 << 21) | (sB << 10);
    if (tid == 0) cnt = 0u;
    __syncthreads();
    const int lw = tid & 63;
    #pragma unroll
    for (int u = 0; u < NFULL; ++u) {
      bool pred = kv[u] >= TB;
      ull mask = __ballot(pred);
      if (mask) {
        int leader = __builtin_ctzll(mask);
        unsigned total = (unsigned)__popcll(mask);
        unsigned basep = 0;
        if (lw == leader) basep = atomicAdd(&cnt, total);
        basep = __shfl(basep, leader);
        if (pred) {
          unsigned p = basep + (unsigned)__popcll(mask & ((1ull << lw) - 1ull));
          unsigned i = (unsigned)(tid + (u << 10));
          if (p < CAP) selPk[p] = ((ull)kv[u] << 32) | (unsigned)(~i);
        }
      }
    }
    if (hastail && ktail >= TB) {
      unsigned p = atomicAdd(&cnt, 1u);
      unsigned i = (unsigned)(tid + NFULL * NT);
      if (p < CAP) selPk[p] = ((ull)ktail << 32) | (unsigned)(~i);
    }
    __syncthreads();
    const unsigned realCnt = (cnt < CAP) ? cnt : CAP;
    for (unsigned i = realCnt + tid; i < CAP; i += NT) selPk[i] = 0ull;
    __syncthreads();
  }

  // ---- hybrid bitonic sort 2048 descending, 2 elem/thread ----
  {
    const int w = tid >> 6, L = tid & 63;
    const int ea = (w << 7) | (L << 1);
    ull a = selPk[ea], bb = selPk[ea + 1];
    #pragma unroll
    for (unsigned k = 2; k <= 128; k <<= 1) {
      #pragma unroll
      for (unsigned j = k >> 1; j >= 2; j >>= 1) {
        bool up = ((ea & k) == 0);
        bool lower = ((ea & j) == 0);
        bool takeMax = (up == lower);
        ull oa = __shfl_xor(a, (int)(j >> 1));
        ull ob = __shfl_xor(bb, (int)(j >> 1));
        a  = takeMax ? (a  > oa ? a  : oa) : (a  < oa ? a  : oa);
        bb = takeMax ? (bb > ob ? bb : ob) : (bb < ob ? bb : ob);
      }
      bool up = ((ea & k) == 0);
      ull mx = a > bb ? a : bb, mn = a > bb ? bb : a;
      a = up ? mx : mn; bb = up ? mn : mx;
    }
    selPk[ea] = a; selPk[ea + 1] = bb;
    __syncthreads();
    for (unsigned k = 256; k <= 2048; k <<= 1) {
      for (unsigned j = k >> 1; j >= 128; j >>= 1) {
        unsigned p = (unsigned)tid;
        unsigned vi = ((p & ~(j - 1)) << 1) | (p & (j - 1));
        unsigned li = vi | j;
        ull av = selPk[vi], cv = selPk[li];
        bool doswap = ((vi & k) == 0) ? (av < cv) : (av > cv);
        if (doswap) { selPk[vi] = cv; selPk[li] = av; }
        __syncthreads();
      }
      a = selPk[ea]; bb = selPk[ea + 1];
      bool up = (((unsigned)(w << 7) & k) == 0);
      #pragma unroll
      for (unsigned j = 64; j >= 2; j >>= 1) {
        bool lower = ((ea & j) == 0);
        bool takeMax = (up == lower);
        ull oa = __shfl_xor(a, (int)(j >> 1));
        ull ob = __shfl_xor(bb, (int)(j >> 1));
        a  = takeMax ? (a  > oa ? a  : oa) : (a  < oa ? a  : oa);
        bb = takeMax ? (bb > ob ? bb : ob) : (bb < ob ? bb : ob);
      }
      ull mx = a > bb ? a : bb, mn = a > bb ? bb : a;
      a = up ? mx : mn; bb = up ? mn : mx;
      selPk[ea] = a; selPk[ea + 1] = bb;
      __syncthreads();
    }
  }

  // ---- decode first 1000 into stride-17 scalar LDS arrays (conflict-free) ----
  if (tid < KSEL) {
    unsigned idx = ~(unsigned)selPk[tid];
    const float2* e2 = (const float2*)(xb + (size_t)idx * 6 + 2);
    float2 ra = e2[0], rb = e2[1];
    unsigned pp = (idx / 9u) % 60u;
    unsigned qq = idx / 540u;
    unsigned sr = idx % 9u;
    const float* ap = anch + (((pp * 40u + qq) * 9u + sr) * 4u);
    float ax = ap[0], ay = ap[1], aw = ap[2], ah = ap[3];
    float xc = ra.x * aw + ax;
    float yc = ra.y * ah + ay;
    float w = aw * expf(rb.x);
    float h = ah * expf(rb.y);
    int a = (tid >> 4) * 17 + (tid & 15);
    px1[a] = xc - 0.5f * w; px2[a] = xc + 0.5f * w;
    py1[a] = yc - 0.5f * h; py2[a] = yc + 0.5f * h;
  }
  __syncthreads();

  // ---- ballot-NMS on wave 0: coords from LDS, tiny register state ----
  if (tid < 64) {
    const int lane = tid;
    unsigned alive = 0u;
    #pragma unroll
    for (int ss = 0; ss < 16; ++ss) {
      int r = lane * 16 + ss;
      alive |= (r < KSEL ? 1u : 0u) << ss;
    }
    int nk = 0;
    while (nk < MAXB) {
      ull bal = __ballot(alive != 0u);
      if (!bal) break;
      int F = __builtin_ctzll(bal);
      int myss = (int)__builtin_ctz(alive | 0x10000u);
      int ssw = __shfl(myss, F);
      int m = F * 16 + ssw;
      if (lane == 0) keptRank[nk] = m;
      int am = (m >> 4) * 17 + (m & 15);
      float wx1 = px1[am], wy1 = py1[am], wx2 = px2[am], wy2 = py2[am];
      ++nk;
      if (nk >= MAXB) break;
      #pragma unroll
      for (int ss = 0; ss < 16; ++ss) {
        if (alive & (1u << ss)) {
          int a = lane * 17 + ss;
          float x1 = px1[a], y1 = py1[a], x2 = px2[a], y2 = py2[a];
          float iw = fmaxf(fminf(x2, wx2) - fmaxf(x1, wx1), 0.f);
          float ih = fmaxf(fminf(y2, wy2) - fmaxf(y1, wy1), 0.f);
          float ar = (x2 - x1) * (y2 - y1);
          if (iw * ih / ar > 0.5f) alive &= ~(1u << ss);  // winner self-clears
        }
      }
    }
    if (lane == 0) numKept = nk;
  }
  __syncthreads();

  // ---- output: kept rows then pad rows cand[j - n]; score from key bits ----
  const int n = numKept;
  if (tid < MAXB) {
    int j = tid;
    int r = (j < n) ? keptRank[j] : (j - n);
    ull pk = selPk[r];
    unsigned idx = ~(unsigned)pk;
    float sc = unfkey((unsigned)(pk >> 32));
    const float2* e2 = (const float2*)(xb + (size_t)idx * 6 + 2);
    float2 ra = e2[0], rb = e2[1];
    unsigned pp = (idx / 9u) % 60u;
    unsigned qq = idx / 540u;
    unsigned sr = idx % 9u;
    const float* ap = anch + (((pp * 40u + qq) * 9u + sr) * 4u);
    float ax = ap[0], ay = ap[1], aw = ap[2], ah = ap[3];
    float xc = ra.x * aw + ax;
    float yc = ra.y * ah + ay;
    float w = aw * expf(rb.x);
    float h = ah * expf(rb.y);
    float* o = out + s * (MAXB * 5) + j * 5;
    o[0] = xc; o[1] = yc; o[2] = w; o[3] = h; o[4] = sc;
  }
}

extern "C" void kernel_launch(void* const* d_in, const int* in_sizes, int n_in,
                              void* d_out, int out_size, void* d_ws, size_t ws_size,
                              hipStream_t stream) {
  const float* x = (const float*)d_in[0];
  const float* anch = (const float*)d_in[1];
  float* out = (float*)d_out;
  const int B = in_sizes[0] / (NELEM * 6);
  ull* gselPk = (ull*)d_ws;                                 // B*2048 u64
  unsigned* ghist = (unsigned*)(gselPk + (size_t)B * CAP);  // B*4*2048 u32
  unsigned* gkeys = ghist + (size_t)B * NCHUNK * 2048;      // B*21600 u32
  unsigned* gcnt = gkeys + (size_t)B * NELEM;               // B u32
  unsigned* gflag = gcnt + B;                               // B u32
  k1_scan<<<dim3(B * NCHUNK), dim3(NT), 0, stream>>>(x, gkeys, ghist, gcnt, gflag);
  k2_compact<<<dim3(B * NCHUNK), dim3(NT), 0, stream>>>(gkeys, ghist, gselPk, gcnt, gflag);
  k3_final<<<dim3(B), dim3(NT), 0, stream>>>(x, anch, gkeys, ghist, gselPk, gcnt, gflag, out);
}